// Round 5
// baseline (204.835 us; speedup 1.0000x reference)
//
#include <hip/hip_runtime.h>

#define MAGIC0  0x51C0DE01u
#define MAGICW0 0x51C0DE02u
#define MAGIC1  0x51C0DE03u
#define MAGICW1 0x51C0DE04u
#define MAGIC2  0x51C0DE05u

__device__ __forceinline__ void spin_eq(const unsigned* p, unsigned v) {
    while (__hip_atomic_load(p, __ATOMIC_ACQUIRE, __HIP_MEMORY_SCOPE_AGENT) != v)
        __builtin_amdgcn_s_sleep(2);
}

// Single fused capsule-routing kernel. grid 512 = b(32) x ch(16), 256 thr.
// Block (b,ch): owns l-tile [ch*128, ch*128+128) of batch b (staged in LDS once)
// and capsules {2ch, 2ch+1} for all caps/squash phases.
// Cross-block sync: per-batch MAGIC flags in ws (poisoned 0xAA each launch).
__global__ __launch_bounds__(256, 2) void k_all(
    const float* __restrict__ u,     // [32,2048,64]
    const float* __restrict__ W,     // [64,512]
    float* __restrict__ out,         // [32,32,16]
    float* __restrict__ part0,       // ws [512][64] colsum partials
    float* __restrict__ wt,          // ws [32][32][64] wtilde
    float* __restrict__ vA,          // ws [512][2048] route-1 partials
    float* __restrict__ vB,          // ws [512][2048] route-2 partials
    unsigned* __restrict__ flags)    // ws [5][512]
{
    const int bid  = blockIdx.x;
    const int b    = bid >> 4;
    const int ch   = bid & 15;
    const int t    = threadIdx.x;
    const int w    = t >> 6;
    const int lane = t & 63;
    const int lr   = lane & 7;
    const int lc   = lane >> 3;

    unsigned* done0 = flags;
    unsigned* fw0   = flags + 512;
    unsigned* d1    = flags + 1024;
    unsigned* fw1   = flags + 1536;
    unsigned* d2    = flags + 2048;

    __shared__ float uS[128 * 68];   // 34816 B, row stride 17 float4 (persistent)
    __shared__ float wS[32 * 68];    //  8704 B
    __shared__ float cR[4096];       // 16384 B scratch
    float4* uS4 = (float4*)uS;
    float4* wS4 = (float4*)wS;
    float4* cR4 = (float4*)cR;

    //---- stage u tile [128][64] + column-sum partial --------------------------
    {
        const float4* ug = (const float4*)(u + (b * 2048 + ch * 128) * 64);
        float4 ca = {0.f, 0.f, 0.f, 0.f};
#pragma unroll
        for (int r = 0; r < 8; ++r) {
            int idx = t + 256 * r;                  // row=idx>>4, col4=idx&15 (=t&15)
            float4 x = ug[idx];
            uS4[(idx >> 4) * 17 + (idx & 15)] = x;
            ca.x += x.x; ca.y += x.y; ca.z += x.z; ca.w += x.w;
        }
        cR4[(t >> 4) * 16 + (t & 15)] = ca;
    }
    __syncthreads();
    if (t < 64) {
        float s = 0.f;
#pragma unroll
        for (int rg = 0; rg < 16; ++rg) s += cR[rg * 64 + t];
        part0[bid * 64 + t] = s;
    }
    __syncthreads();
    if (t == 0) {
        __threadfence();
        __hip_atomic_store(done0 + bid, MAGIC0, __ATOMIC_RELEASE, __HIP_MEMORY_SCOPE_AGENT);
    }

    //---- caps: fold V -> project 2 capsules -> squash -> wtil/out -------------
    auto caps = [&](int mode, const float* vsrc, bool emit_out) {
        if (mode == 0) {
            if (t < 64) {
                float s = 0.f;
#pragma unroll
                for (int c2 = 0; c2 < 16; ++c2) s += vsrc[(b * 16 + c2) * 64 + t];
                cR[t] = s * (1.0f / 32.0f);          // v0 (broadcast over n)
            }
        } else {
            if (t < 128) {
                int nl = t >> 6, i = t & 63, n = 2 * ch + nl;
                float s = 0.f;
#pragma unroll
                for (int c2 = 0; c2 < 16; ++c2)
                    s += vsrc[(b * 16 + c2) * 2048 + n * 64 + i];
                cR[nl * 65 + i] = s;
            }
        }
        __syncthreads();
        if (t < 32) {
            int nl = t >> 4, d = t & 15, n = 2 * ch + nl;
            const float* vp = (mode == 0) ? cR : (cR + nl * 65);
            float s = 0.f;
#pragma unroll
            for (int i = 0; i < 64; ++i)
                s = fmaf(vp[i], W[i * 512 + n * 16 + d], s);
            float s2 = s * s;
            s2 += __shfl_xor(s2, 1, 16);
            s2 += __shfl_xor(s2, 2, 16);
            s2 += __shfl_xor(s2, 4, 16);
            s2 += __shfl_xor(s2, 8, 16);
            float o = s / sqrtf(s2 + 1e-7f);
            if (emit_out) out[b * 512 + n * 16 + d] = o;
            else cR[144 + nl * 17 + d] = o;
        }
        if (!emit_out) {
            __syncthreads();
            if (t < 128) {
                int nl = t >> 6, i = t & 63, n = 2 * ch + nl;
                float a = 0.f;
#pragma unroll
                for (int dd = 0; dd < 16; ++dd)
                    a = fmaf(W[i * 512 + n * 16 + dd], cR[144 + nl * 17 + dd], a);
                wt[b * 2048 + n * 64 + i] = a;
            }
            __syncthreads();
        }
    };

    auto load_wt = [&]() {
        const float4* wg = (const float4*)(wt + b * 2048);
#pragma unroll
        for (int r = 0; r < 2; ++r) {
            int idx = t + 256 * r;
            wS4[(idx >> 4) * 17 + (idx & 15)] = wg[idx];
        }
        __syncthreads();
    };

    //---- route: logits 128lx32n -> softmax(n) -> V partial (R4-validated) -----
    auto route = [&](float* vtgt, unsigned* df, unsigned magic) {
        float acc[4][4];
#pragma unroll
        for (int i = 0; i < 4; ++i)
#pragma unroll
            for (int j = 0; j < 4; ++j) acc[i][j] = 0.f;
        const int arow = w * 32 + lr;
#pragma unroll 4
        for (int k4 = 0; k4 < 16; ++k4) {
            float4 wf[4];
#pragma unroll
            for (int j = 0; j < 4; ++j) wf[j] = wS4[(lc + 8 * j) * 17 + k4];
#pragma unroll
            for (int i = 0; i < 4; ++i) {
                float4 a = uS4[(arow + 8 * i) * 17 + k4];
#pragma unroll
                for (int j = 0; j < 4; ++j) {
                    acc[i][j] = fmaf(a.x, wf[j].x, acc[i][j]);
                    acc[i][j] = fmaf(a.y, wf[j].y, acc[i][j]);
                    acc[i][j] = fmaf(a.z, wf[j].z, acc[i][j]);
                    acc[i][j] = fmaf(a.w, wf[j].w, acc[i][j]);
                }
            }
        }
#pragma unroll
        for (int i = 0; i < 4; ++i) {
            float m = fmaxf(fmaxf(acc[i][0], acc[i][1]), fmaxf(acc[i][2], acc[i][3]));
            m = fmaxf(m, __shfl_xor(m, 8));
            m = fmaxf(m, __shfl_xor(m, 16));
            m = fmaxf(m, __shfl_xor(m, 32));
            float e0 = __expf(acc[i][0] - m);
            float e1 = __expf(acc[i][1] - m);
            float e2 = __expf(acc[i][2] - m);
            float e3 = __expf(acc[i][3] - m);
            float ss = e0 + e1 + e2 + e3;
            ss += __shfl_xor(ss, 8);
            ss += __shfl_xor(ss, 16);
            ss += __shfl_xor(ss, 32);
            float inv = 1.f / ss;
            float4 cv = {e0 * inv, e1 * inv, e2 * inv, e3 * inv};
            cR4[(arow + 8 * i) * 8 + lc] = cv;
        }
        __syncthreads();
        float vacc[4][8];
#pragma unroll
        for (int j = 0; j < 4; ++j)
#pragma unroll
            for (int k = 0; k < 8; ++k) vacc[j][k] = 0.f;
#pragma unroll 4
        for (int lrel = 0; lrel < 32; ++lrel) {
            int l = w * 32 + lrel;
            float4 cv = cR4[l * 8 + lc];
            float4 u0 = uS4[l * 17 + lr * 2];
            float4 u1 = uS4[l * 17 + lr * 2 + 1];
            const float* cp = (const float*)&cv;
#pragma unroll
            for (int j = 0; j < 4; ++j) {
                float c = cp[j];
                vacc[j][0] = fmaf(c, u0.x, vacc[j][0]);
                vacc[j][1] = fmaf(c, u0.y, vacc[j][1]);
                vacc[j][2] = fmaf(c, u0.z, vacc[j][2]);
                vacc[j][3] = fmaf(c, u0.w, vacc[j][3]);
                vacc[j][4] = fmaf(c, u1.x, vacc[j][4]);
                vacc[j][5] = fmaf(c, u1.y, vacc[j][5]);
                vacc[j][6] = fmaf(c, u1.z, vacc[j][6]);
                vacc[j][7] = fmaf(c, u1.w, vacc[j][7]);
            }
        }
        __syncthreads();
        if (w >= 2) {
            float4* red = cR4 + (w - 2) * 512;
#pragma unroll
            for (int j = 0; j < 4; ++j) {
                int n = lc + 8 * j;
                float4 r0 = {vacc[j][0], vacc[j][1], vacc[j][2], vacc[j][3]};
                float4 r1 = {vacc[j][4], vacc[j][5], vacc[j][6], vacc[j][7]};
                red[n * 16 + lr * 2]     = r0;
                red[n * 16 + lr * 2 + 1] = r1;
            }
        }
        __syncthreads();
        if (w < 2) {
            const float4* red = cR4 + w * 512;
#pragma unroll
            for (int j = 0; j < 4; ++j) {
                int n = lc + 8 * j;
                float4 r0 = red[n * 16 + lr * 2];
                float4 r1 = red[n * 16 + lr * 2 + 1];
                vacc[j][0] += r0.x; vacc[j][1] += r0.y;
                vacc[j][2] += r0.z; vacc[j][3] += r0.w;
                vacc[j][4] += r1.x; vacc[j][5] += r1.y;
                vacc[j][6] += r1.z; vacc[j][7] += r1.w;
            }
        }
        __syncthreads();
        if (w == 1) {
            float4* red = cR4 + 512;
#pragma unroll
            for (int j = 0; j < 4; ++j) {
                int n = lc + 8 * j;
                float4 r0 = {vacc[j][0], vacc[j][1], vacc[j][2], vacc[j][3]};
                float4 r1 = {vacc[j][4], vacc[j][5], vacc[j][6], vacc[j][7]};
                red[n * 16 + lr * 2]     = r0;
                red[n * 16 + lr * 2 + 1] = r1;
            }
        }
        __syncthreads();
        if (w == 0) {
            const float4* red = cR4 + 512;
            float4* out4 = (float4*)(vtgt + bid * 2048);
#pragma unroll
            for (int j = 0; j < 4; ++j) {
                int n = lc + 8 * j;
                float4 r0 = red[n * 16 + lr * 2];
                float4 r1 = red[n * 16 + lr * 2 + 1];
                float4 o0 = {vacc[j][0] + r0.x, vacc[j][1] + r0.y,
                             vacc[j][2] + r0.z, vacc[j][3] + r0.w};
                float4 o1 = {vacc[j][4] + r1.x, vacc[j][5] + r1.y,
                             vacc[j][6] + r1.z, vacc[j][7] + r1.w};
                out4[n * 16 + lr * 2]     = o0;
                out4[n * 16 + lr * 2 + 1] = o1;
            }
        }
        __syncthreads();
        if (t == 0) {
            __threadfence();
            __hip_atomic_store(df + bid, magic, __ATOMIC_RELEASE, __HIP_MEMORY_SCOPE_AGENT);
        }
    };

    //---- schedule -------------------------------------------------------------
    if (t < 16) spin_eq(done0 + b * 16 + t, MAGIC0);
    __syncthreads();
    caps(0, part0, false);
    if (t == 0) {
        __threadfence();
        __hip_atomic_store(fw0 + bid, MAGICW0, __ATOMIC_RELEASE, __HIP_MEMORY_SCOPE_AGENT);
    }
    if (t < 16) spin_eq(fw0 + b * 16 + t, MAGICW0);
    __syncthreads();
    load_wt();
    route(vA, d1, MAGIC1);

    if (t < 16) spin_eq(d1 + b * 16 + t, MAGIC1);
    __syncthreads();
    caps(1, vA, false);
    if (t == 0) {
        __threadfence();
        __hip_atomic_store(fw1 + bid, MAGICW1, __ATOMIC_RELEASE, __HIP_MEMORY_SCOPE_AGENT);
    }
    if (t < 16) spin_eq(fw1 + b * 16 + t, MAGICW1);
    __syncthreads();
    load_wt();
    route(vB, d2, MAGIC2);

    if (t < 16) spin_eq(d2 + b * 16 + t, MAGIC2);
    __syncthreads();
    caps(1, vB, true);
}

extern "C" void kernel_launch(void* const* d_in, const int* in_sizes, int n_in,
                              void* d_out, int out_size, void* d_ws, size_t ws_size,
                              hipStream_t stream) {
    const float* u = (const float*)d_in[0];   // [32,2048,64] f32
    const float* W = (const float*)d_in[1];   // [1,64,512]   f32
    float* out = (float*)d_out;               // [32,32,16]   f32
    float* ws  = (float*)d_ws;
    float* part0 = ws;                        // 32768 f
    float* wt    = ws + 32768;                // 65536 f
    float* vA    = ws + 98304;                // 1048576 f
    float* vB    = ws + 1146880;              // 1048576 f
    unsigned* flags = (unsigned*)(ws + 2195456);  // 2560 u32 (0xAA-poisoned)

    k_all<<<512, 256, 0, stream>>>(u, W, out, part0, wt, vA, vB, flags);
}

// Round 6
// 109.823 us; speedup vs baseline: 1.8651x; 1.8651x over previous
//
#include <hip/hip_runtime.h>

#define LSEQ 2048
#define NC 32
#define DC 16

// ---------------------------------------------------------------------------
// k_sum_u: per-block partial column sums of u over 256 l's. (validated R2/R4)
// grid 256 (b = bid>>3, chunk = bid&7), 256 threads. Writes part0[bid][64].
// ---------------------------------------------------------------------------
__global__ __launch_bounds__(256) void k_sum_u(const float* __restrict__ u,
                                               float* __restrict__ part0) {
    int b  = blockIdx.x >> 3;
    int l0 = (blockIdx.x & 7) * 256;
    int q  = threadIdx.x & 15;
    int r  = threadIdx.x >> 4;
    const float4* u4 = (const float4*)u;
    float4 acc = {0.f, 0.f, 0.f, 0.f};
#pragma unroll
    for (int j = 0; j < 16; ++j) {
        int l = l0 + r + 16 * j;
        float4 x = u4[(b * LSEQ + l) * 16 + q];
        acc.x += x.x; acc.y += x.y; acc.z += x.z; acc.w += x.w;
    }
    __shared__ float red[16][64];
    red[r][q * 4 + 0] = acc.x;
    red[r][q * 4 + 1] = acc.y;
    red[r][q * 4 + 2] = acc.z;
    red[r][q * 4 + 3] = acc.w;
    __syncthreads();
    if (threadIdx.x < 64) {
        float s = 0.f;
#pragma unroll
        for (int rr = 0; rr < 16; ++rr) s += red[rr][threadIdx.x];
        part0[blockIdx.x * 64 + threadIdx.x] = s;
    }
}

// ---------------------------------------------------------------------------
// k_route<MODE>: inline caps (fold V -> project W -> squash -> wtil in LDS),
// then register-tiled routing pass; per-block V partials out (no atomics).
// MODE 0: vsrc = part0 [32*8][64] (broadcast v, scale 1/32)
// MODE 1: vsrc = vpart [32*16][2048] (fold 16 chunk partials)
// grid 512 = b(32) x ch(16), 512 threads (8 waves); block owns 128 l's.
// Phase A: 8 waves x 16 l (per-lane 2l x 4n); phase B: waves 0-3 x 32 l.
// ---------------------------------------------------------------------------
template <int MODE>
__global__ __launch_bounds__(512, 4) void k_route(
    const float* __restrict__ u,
    const float* __restrict__ W,
    const float* __restrict__ vsrc,
    float* __restrict__ vout)       // [512][2048]
{
    const int bid  = blockIdx.x;
    const int b    = bid >> 4;
    const int ch   = bid & 15;
    const int t    = threadIdx.x;
    const int w    = t >> 6;
    const int lane = t & 63;
    const int lr   = lane & 7;
    const int lc   = lane >> 3;

    __shared__ float uS[128 * 68];   // 34816 B, row stride 17 float4
    __shared__ float wS[32 * 68];    //  8704 B, wtil rows
    __shared__ float cR[4096];       // 16384 B scratch: vS/oS, softmax c, fold
    float4* uS4 = (float4*)uS;
    float4* wS4 = (float4*)wS;
    float4* cR4 = (float4*)cR;

    // ---- stage u tile [128][64] ----
    const float4* ug = (const float4*)(u + (b * LSEQ + ch * 128) * 64);
#pragma unroll
    for (int r = 0; r < 4; ++r) {
        int idx = t + 512 * r;                    // 0..2047, row=idx>>4, col=idx&15
        uS4[(idx >> 4) * 17 + (idx & 15)] = ug[idx];
    }

    // ---- fold V partials into cR (vS) ----
    if (MODE == 0) {
        if (t < 64) {
            float s = 0.f;
#pragma unroll
            for (int c2 = 0; c2 < 8; ++c2) s += vsrc[(b * 8 + c2) * 64 + t];
            cR[t] = s * (1.0f / 32.0f);           // broadcast v0
        }
    } else {
#pragma unroll
        for (int r = 0; r < 4; ++r) {
            int e = t + 512 * r;                  // n = e>>6, i = e&63
            float s = 0.f;
#pragma unroll
            for (int c2 = 0; c2 < 16; ++c2) s += vsrc[(b * 16 + c2) * 2048 + e];
            cR[(e >> 6) * 65 + (e & 63)] = s;     // vS stride 65 (bank-free)
        }
    }
    __syncthreads();

    // ---- projection s = V @ W_n + squash -> oS (stride 17), all 512 thr ----
    float* oS = cR + 2112;                        // [32][17] = 544 floats
    {
        int n0 = t >> 4;                          // 0..31
        const float* vp = (MODE == 0) ? cR : (cR + n0 * 65);
        float s = 0.f;
#pragma unroll
        for (int i = 0; i < 64; ++i)
            s = fmaf(vp[i], W[i * 512 + t], s);   // c = t (coalesced)
        float q = s * s;
#pragma unroll
        for (int off = 1; off <= 8; off <<= 1) q += __shfl_xor(q, off, 16);
        oS[n0 * 17 + (t & 15)] = s / sqrtf(q + 1e-7f);
    }
    __syncthreads();

    // ---- wtil[n][i] = (W_n @ o_n)[i] -> wS ----
#pragma unroll
    for (int r = 0; r < 4; ++r) {
        int e = t + 512 * r;
        int n = e & 31, i = e >> 5;
        const float4* Wr = (const float4*)(W + i * 512 + n * 16);
        float a = 0.f;
#pragma unroll
        for (int q = 0; q < 4; ++q) {
            float4 wv = Wr[q];
            a = fmaf(wv.x, oS[n * 17 + 4 * q + 0], a);
            a = fmaf(wv.y, oS[n * 17 + 4 * q + 1], a);
            a = fmaf(wv.z, oS[n * 17 + 4 * q + 2], a);
            a = fmaf(wv.w, oS[n * 17 + 4 * q + 3], a);
        }
        wS[n * 68 + i] = a;
    }
    __syncthreads();

    // ---- phase A: logits, wave w owns l in [w*16, w*16+16); lane 2l x 4n ----
    float acc[2][4];
#pragma unroll
    for (int i = 0; i < 2; ++i)
#pragma unroll
        for (int j = 0; j < 4; ++j) acc[i][j] = 0.f;
    const int la = w * 16 + lr * 2;               // + ii
#pragma unroll 4
    for (int k4 = 0; k4 < 16; ++k4) {
        float4 wf[4];
#pragma unroll
        for (int j = 0; j < 4; ++j) wf[j] = wS4[(lc + 8 * j) * 17 + k4];
#pragma unroll
        for (int ii = 0; ii < 2; ++ii) {
            float4 a = uS4[(la + ii) * 17 + k4];
#pragma unroll
            for (int j = 0; j < 4; ++j) {
                acc[ii][j] = fmaf(a.x, wf[j].x, acc[ii][j]);
                acc[ii][j] = fmaf(a.y, wf[j].y, acc[ii][j]);
                acc[ii][j] = fmaf(a.z, wf[j].z, acc[ii][j]);
                acc[ii][j] = fmaf(a.w, wf[j].w, acc[ii][j]);
            }
        }
    }

    // ---- softmax over n = lc+8j (reduce over lane bits 3..5) ----
#pragma unroll
    for (int ii = 0; ii < 2; ++ii) {
        int l = la + ii;
        float m = fmaxf(fmaxf(acc[ii][0], acc[ii][1]), fmaxf(acc[ii][2], acc[ii][3]));
        m = fmaxf(m, __shfl_xor(m, 8));
        m = fmaxf(m, __shfl_xor(m, 16));
        m = fmaxf(m, __shfl_xor(m, 32));
        float e0 = __expf(acc[ii][0] - m);
        float e1 = __expf(acc[ii][1] - m);
        float e2 = __expf(acc[ii][2] - m);
        float e3 = __expf(acc[ii][3] - m);
        float ss = e0 + e1 + e2 + e3;
        ss += __shfl_xor(ss, 8);
        ss += __shfl_xor(ss, 16);
        ss += __shfl_xor(ss, 32);
        float inv = 1.f / ss;
        float4 cv = {e0 * inv, e1 * inv, e2 * inv, e3 * inv};
        cR4[l * 8 + (lc ^ (l & 7))] = cv;         // XOR-swizzled: 2-way max
    }
    __syncthreads();

    // ---- phase B (waves 0-3): V[n=lc+8j][d=lr*8..+7] over wave's 32 l's ----
    float vacc[4][8];
#pragma unroll
    for (int j = 0; j < 4; ++j)
#pragma unroll
        for (int k = 0; k < 8; ++k) vacc[j][k] = 0.f;
    if (w < 4) {
#pragma unroll 4
        for (int lrel = 0; lrel < 32; ++lrel) {
            int l = w * 32 + lrel;
            float4 cv = cR4[l * 8 + (lc ^ (l & 7))];
            float4 u0 = uS4[l * 17 + lr * 2];
            float4 u1 = uS4[l * 17 + lr * 2 + 1];
            const float* cp = (const float*)&cv;
#pragma unroll
            for (int j = 0; j < 4; ++j) {
                float c = cp[j];
                vacc[j][0] = fmaf(c, u0.x, vacc[j][0]);
                vacc[j][1] = fmaf(c, u0.y, vacc[j][1]);
                vacc[j][2] = fmaf(c, u0.z, vacc[j][2]);
                vacc[j][3] = fmaf(c, u0.w, vacc[j][3]);
                vacc[j][4] = fmaf(c, u1.x, vacc[j][4]);
                vacc[j][5] = fmaf(c, u1.y, vacc[j][5]);
                vacc[j][6] = fmaf(c, u1.z, vacc[j][6]);
                vacc[j][7] = fmaf(c, u1.w, vacc[j][7]);
            }
        }
    }
    __syncthreads();                              // all cR reads done

    // ---- cross-wave fold among waves 0-3: 4 -> 2 -> 1 -> store ----
    if (w == 2 || w == 3) {
        float4* red = cR4 + (w - 2) * 512;
#pragma unroll
        for (int j = 0; j < 4; ++j) {
            int n = lc + 8 * j;
            float4 r0 = {vacc[j][0], vacc[j][1], vacc[j][2], vacc[j][3]};
            float4 r1 = {vacc[j][4], vacc[j][5], vacc[j][6], vacc[j][7]};
            red[n * 16 + lr * 2]     = r0;
            red[n * 16 + lr * 2 + 1] = r1;
        }
    }
    __syncthreads();
    if (w < 2) {
        const float4* red = cR4 + w * 512;
#pragma unroll
        for (int j = 0; j < 4; ++j) {
            int n = lc + 8 * j;
            float4 r0 = red[n * 16 + lr * 2];
            float4 r1 = red[n * 16 + lr * 2 + 1];
            vacc[j][0] += r0.x; vacc[j][1] += r0.y;
            vacc[j][2] += r0.z; vacc[j][3] += r0.w;
            vacc[j][4] += r1.x; vacc[j][5] += r1.y;
            vacc[j][6] += r1.z; vacc[j][7] += r1.w;
        }
    }
    __syncthreads();
    if (w == 1) {
        float4* red = cR4 + 512;
#pragma unroll
        for (int j = 0; j < 4; ++j) {
            int n = lc + 8 * j;
            float4 r0 = {vacc[j][0], vacc[j][1], vacc[j][2], vacc[j][3]};
            float4 r1 = {vacc[j][4], vacc[j][5], vacc[j][6], vacc[j][7]};
            red[n * 16 + lr * 2]     = r0;
            red[n * 16 + lr * 2 + 1] = r1;
        }
    }
    __syncthreads();
    if (w == 0) {
        const float4* red = cR4 + 512;
        float4* out4 = (float4*)(vout + bid * 2048);
#pragma unroll
        for (int j = 0; j < 4; ++j) {
            int n = lc + 8 * j;
            float4 r0 = red[n * 16 + lr * 2];
            float4 r1 = red[n * 16 + lr * 2 + 1];
            float4 o0 = {vacc[j][0] + r0.x, vacc[j][1] + r0.y,
                         vacc[j][2] + r0.z, vacc[j][3] + r0.w};
            float4 o1 = {vacc[j][4] + r1.x, vacc[j][5] + r1.y,
                         vacc[j][6] + r1.z, vacc[j][7] + r1.w};
            out4[n * 16 + lr * 2]     = o0;
            out4[n * 16 + lr * 2 + 1] = o1;
        }
    }
}

// ---------------------------------------------------------------------------
// k_caps_final: fold 16 route partials -> project -> squash -> out. (R4 code)
// grid 256 (b = bid>>3, ng = bid&7 -> capsules ng*4..+3), 64 threads.
// ---------------------------------------------------------------------------
__global__ __launch_bounds__(64) void k_caps_final(const float* __restrict__ v,
                                                   const float* __restrict__ W,
                                                   float* __restrict__ out) {
    int b  = blockIdx.x >> 3;
    int ng = blockIdx.x & 7;
    int t  = threadIdx.x;
    __shared__ float vS[4][72];
    {
        int row = t >> 4, col4 = t & 15;
        const float4* v4 = (const float4*)v;
        float4 a = {0.f, 0.f, 0.f, 0.f};
#pragma unroll
        for (int c2 = 0; c2 < 16; ++c2) {
            float4 x = v4[(b * 16 + c2) * 512 + (ng * 4 + row) * 16 + col4];
            a.x += x.x; a.y += x.y; a.z += x.z; a.w += x.w;
        }
        ((float4*)&vS[row][0])[col4] = a;
    }
    __syncthreads();
    int n4 = t >> 4, d = t & 15;
    int n  = ng * 4 + n4;
    const float* vrow = &vS[n4][0];
    float s = 0.f;
#pragma unroll
    for (int i = 0; i < 64; ++i)
        s = fmaf(vrow[i], W[i * (NC * DC) + n * DC + d], s);
    float s2 = s * s;
#pragma unroll
    for (int off = 8; off >= 1; off >>= 1) s2 += __shfl_xor(s2, off, 16);
    out[b * (NC * DC) + n * DC + d] = s / sqrtf(s2 + 1e-7f);
}

extern "C" void kernel_launch(void* const* d_in, const int* in_sizes, int n_in,
                              void* d_out, int out_size, void* d_ws, size_t ws_size,
                              hipStream_t stream) {
    const float* u = (const float*)d_in[0];   // [32,2048,64] f32
    const float* W = (const float*)d_in[1];   // [1,64,512]   f32
    float* out = (float*)d_out;               // [32,32,16]   f32
    float* ws  = (float*)d_ws;
    float* part0  = ws;                       // 256*64    = 16384 floats
    float* vpartA = ws + 16384;               // 512*2048  floats (4 MB)
    float* vpartB = vpartA + 512 * 2048;      // 512*2048  floats (4 MB)

    k_sum_u<<<256, 256, 0, stream>>>(u, part0);
    k_route<0><<<512, 512, 0, stream>>>(u, W, part0, vpartA);
    k_route<1><<<512, 512, 0, stream>>>(u, W, vpartA, vpartB);
    k_caps_final<<<256, 64, 0, stream>>>(vpartB, W, out);
}